// Round 4
// baseline (1969.984 us; speedup 1.0000x reference)
//
#include <hip/hip_runtime.h>

#define NB 8
#define NN 2048
#define MM 2048
#define DD 64
#define NMAT ((size_t)NN * (size_t)MM)

// ---------------------------------------------------------------------------
// Static device scratch. Four fp32 cost slabs (Cyx materialized via a
// cost_kernel call with arguments swapped — bit-exact transpose of Cxy).
// ---------------------------------------------------------------------------
__device__ float g_Cxy[NB * NMAT];
__device__ float g_Cyx[NB * NMAT];
__device__ float g_Cxx[NB * NMAT];
__device__ float g_Cyy[NB * NMAT];
// potential banks: [0]/[1] = carry double-buffer, [2] = final
__device__ float g_fab[3][NB * NN], g_gba[3][NB * NN];
__device__ float g_faa[3][NB * NN], g_gbb[3][NB * NN];
__device__ float g_alog[NB * NN], g_blog[NB * NN];
__device__ float g_xn[NB * NN], g_yn[NB * NN];
// per-iteration h vectors for the four softmin problems
__device__ float g_h0[NB * MM], g_h1[NB * NN], g_h2[NB * NN], g_h3[NB * MM];

// ---------------------------------------------------------------------------
// prep: a_log/b_log = log(w), xn/yn = 0.5*||row||^2 (one row per wave)
// ---------------------------------------------------------------------------
__global__ __launch_bounds__(256) void prep_kernel(
    const float* __restrict__ x, const float* __restrict__ y,
    const float* __restrict__ w1, const float* __restrict__ w2)
{
  int gid = blockIdx.x * 256 + threadIdx.x;
  if (gid < NB * NN) {
    g_alog[gid] = logf(w1[gid]);
    g_blog[gid] = logf(w2[gid]);
  }
  int lane = threadIdx.x & 63;
  int row = blockIdx.x * 4 + (threadIdx.x >> 6);   // grid 4096 -> rows 0..16383
  float xv = x[(size_t)row * DD + lane];
  float yv = y[(size_t)row * DD + lane];
  float sx = xv * xv;
  float sy = yv * yv;
#pragma unroll
  for (int off = 32; off > 0; off >>= 1) {
    sx += __shfl_down(sx, off);
    sy += __shfl_down(sy, off);
  }
  if (lane == 0) {
    g_xn[row] = 0.5f * sx;
    g_yn[row] = 0.5f * sy;
  }
}

// ---------------------------------------------------------------------------
// cost GEMM: C[b][i][j] = max(xn_i + yn_j - x_i . y_j, 0), fp32 out.
// 128x128 tile per block (256 threads, 8x8 per thread), K=64 fully staged.
// Called 4x: (x,y)->Cxy, (y,x)->Cyx, (x,x)->Cxx, (y,y)->Cyy.
// ---------------------------------------------------------------------------
__global__ __launch_bounds__(256) void cost_kernel(
    const float* __restrict__ X, const float* __restrict__ Y,
    const float* __restrict__ xn, const float* __restrict__ yn,
    float* __restrict__ C)
{
  __shared__ float Xs[64 * 128];
  __shared__ float Ys[64 * 128];
  const int b = blockIdx.z;
  const int i0 = blockIdx.y * 128;
  const int j0 = blockIdx.x * 128;
  const int t = threadIdx.x;
  const float* xb = X + (size_t)b * NN * DD;
  const float* yb = Y + (size_t)b * MM * DD;

#pragma unroll
  for (int p = 0; p < 8; ++p) {
    int f = p * 256 + t;        // float4 index within 128x64 tile
    int r = f >> 4;
    int k4 = (f & 15) << 2;
    float4 vx = ((const float4*)(xb + (size_t)(i0 + r) * DD))[f & 15];
    Xs[(k4 + 0) * 128 + r] = vx.x;
    Xs[(k4 + 1) * 128 + r] = vx.y;
    Xs[(k4 + 2) * 128 + r] = vx.z;
    Xs[(k4 + 3) * 128 + r] = vx.w;
    float4 vy = ((const float4*)(yb + (size_t)(j0 + r) * DD))[f & 15];
    Ys[(k4 + 0) * 128 + r] = vy.x;
    Ys[(k4 + 1) * 128 + r] = vy.y;
    Ys[(k4 + 2) * 128 + r] = vy.z;
    Ys[(k4 + 3) * 128 + r] = vy.w;
  }
  __syncthreads();

  const int tx = t & 15, ty = t >> 4;
  float acc[8][8];
#pragma unroll
  for (int r = 0; r < 8; ++r)
#pragma unroll
    for (int c = 0; c < 8; ++c) acc[r][c] = 0.f;

#pragma unroll 4
  for (int k = 0; k < 64; ++k) {
    float a[8], bb[8];
    *(float4*)&a[0] = *(const float4*)&Xs[k * 128 + ty * 8];
    *(float4*)&a[4] = *(const float4*)&Xs[k * 128 + ty * 8 + 4];
    *(float4*)&bb[0] = *(const float4*)&Ys[k * 128 + tx * 8];
    *(float4*)&bb[4] = *(const float4*)&Ys[k * 128 + tx * 8 + 4];
#pragma unroll
    for (int r = 0; r < 8; ++r)
#pragma unroll
      for (int c = 0; c < 8; ++c)
        acc[r][c] = fmaf(a[r], bb[c], acc[r][c]);
  }

  float xr[8], yc[8];
#pragma unroll
  for (int r = 0; r < 8; ++r) xr[r] = xn[b * NN + i0 + ty * 8 + r];
#pragma unroll
  for (int c = 0; c < 8; ++c) yc[c] = yn[b * MM + j0 + tx * 8 + c];

#pragma unroll
  for (int r = 0; r < 8; ++r) {
    float* crow = C + (size_t)b * NMAT
                + (size_t)(i0 + ty * 8 + r) * MM + j0 + tx * 8;
    float4 o0, o1;
    o0.x = fmaxf(xr[r] + yc[0] - acc[r][0], 0.f);
    o0.y = fmaxf(xr[r] + yc[1] - acc[r][1], 0.f);
    o0.z = fmaxf(xr[r] + yc[2] - acc[r][2], 0.f);
    o0.w = fmaxf(xr[r] + yc[3] - acc[r][3], 0.f);
    o1.x = fmaxf(xr[r] + yc[4] - acc[r][4], 0.f);
    o1.y = fmaxf(xr[r] + yc[5] - acc[r][5], 0.f);
    o1.z = fmaxf(xr[r] + yc[6] - acc[r][6], 0.f);
    o1.w = fmaxf(xr[r] + yc[7] - acc[r][7], 0.f);
    ((float4*)crow)[0] = o0;
    ((float4*)crow)[1] = o1;
  }
}

// ---------------------------------------------------------------------------
// h-vector prep for one iteration (all four problems):
//   h0 = blog + gs*gba_in   (for f_ab update over Cxy)
//   h1 = alog + gs*fab_in   (for g_ba update over Cyx)
//   h2 = alog + gs*faa_in   (for f_aa update over Cxx)
//   h3 = blog + gs*gbb_in   (for g_bb update over Cyy)
// ---------------------------------------------------------------------------
__global__ __launch_bounds__(256) void hprep_kernel(
    const float* __restrict__ fab_in, const float* __restrict__ gba_in,
    const float* __restrict__ faa_in, const float* __restrict__ gbb_in,
    float gs)
{
  int i = blockIdx.x * 256 + threadIdx.x;   // grid 64 -> 16384
  g_h0[i] = fmaf(gs, gba_in[i], g_blog[i]);
  g_h1[i] = fmaf(gs, fab_in[i], g_alog[i]);
  g_h2[i] = fmaf(gs, faa_in[i], g_alog[i]);
  g_h3[i] = fmaf(gs, gbb_in[i], g_blog[i]);
}

// ---------------------------------------------------------------------------
// simple row softmin: one block per row, strict two-phase max-then-sum.
//   ft = -eps * log sum_j exp(h_j - C[row,j]*inv_eps)
//   fout = alpha*fold + beta*ft
// grid (NN, NB), 256 threads, 8 columns per thread (stride 256).
// ---------------------------------------------------------------------------
__global__ __launch_bounds__(256) void softmin_row(
    const float* __restrict__ C, const float* __restrict__ h,
    const float* __restrict__ fold, float* __restrict__ fout,
    float eps, float inv_eps, float alpha, float beta)
{
  const int b = blockIdx.y;
  const int row = blockIdx.x;
  const int t = threadIdx.x;
  const float* Crow = C + (size_t)b * NMAT + (size_t)row * MM;
  const float* hb = h + (size_t)b * MM;
  __shared__ float red[256];

  float v[8];
  float m = -3.0e38f;
#pragma unroll
  for (int q = 0; q < 8; ++q) {
    int j = q * 256 + t;
    v[q] = fmaf(Crow[j], -inv_eps, hb[j]);
    m = fmaxf(m, v[q]);
  }
  red[t] = m;
  __syncthreads();
  for (int s = 128; s > 0; s >>= 1) {
    if (t < s) red[t] = fmaxf(red[t], red[t + s]);
    __syncthreads();
  }
  float M = red[0];
  __syncthreads();

  float sum = 0.f;
#pragma unroll
  for (int q = 0; q < 8; ++q) sum += expf(v[q] - M);
  red[t] = sum;
  __syncthreads();
  for (int s = 128; s > 0; s >>= 1) {
    if (t < s) red[t] += red[t + s];
    __syncthreads();
  }
  if (t == 0) {
    float ft = -eps * (M + logf(red[0]));
    int idx = b * NN + row;
    fout[idx] = alpha * fold[idx] + beta * ft;
  }
}

// ---------------------------------------------------------------------------
// loss = mean_b [ sum_i w1*(fabf - faaf) + sum_j w2*(gbaf - gbbf) ]
// ---------------------------------------------------------------------------
__global__ __launch_bounds__(256) void loss_kernel(
    const float* __restrict__ w1, const float* __restrict__ w2,
    float* __restrict__ out)
{
  __shared__ float red[256];
  float acc = 0.f;
  for (int idx = threadIdx.x; idx < NB * NN; idx += 256) {
    acc += w1[idx] * (g_fab[2][idx] - g_faa[2][idx])
         + w2[idx] * (g_gba[2][idx] - g_gbb[2][idx]);
  }
  red[threadIdx.x] = acc;
  __syncthreads();
  for (int s = 128; s > 0; s >>= 1) {
    if (threadIdx.x < s) red[threadIdx.x] += red[threadIdx.x + s];
    __syncthreads();
  }
  if (threadIdx.x == 0) out[0] = red[0] * (1.0f / NB);
}

// ---------------------------------------------------------------------------
extern "C" void kernel_launch(void* const* d_in, const int* in_sizes, int n_in,
                              void* d_out, int out_size, void* d_ws, size_t ws_size,
                              hipStream_t stream)
{
  const float* x = (const float*)d_in[0];
  const float* y = (const float*)d_in[1];
  const float* w1 = (const float*)d_in[2];
  const float* w2 = (const float*)d_in[3];
  float* out = (float*)d_out;

  // device-symbol addresses (host-side; resolved at module load)
  float* Cxy;  hipGetSymbolAddress((void**)&Cxy, HIP_SYMBOL(g_Cxy));
  float* Cyx;  hipGetSymbolAddress((void**)&Cyx, HIP_SYMBOL(g_Cyx));
  float* Cxx;  hipGetSymbolAddress((void**)&Cxx, HIP_SYMBOL(g_Cxx));
  float* Cyy;  hipGetSymbolAddress((void**)&Cyy, HIP_SYMBOL(g_Cyy));
  float* xn;   hipGetSymbolAddress((void**)&xn, HIP_SYMBOL(g_xn));
  float* yn;   hipGetSymbolAddress((void**)&yn, HIP_SYMBOL(g_yn));
  float* h0;   hipGetSymbolAddress((void**)&h0, HIP_SYMBOL(g_h0));
  float* h1;   hipGetSymbolAddress((void**)&h1, HIP_SYMBOL(g_h1));
  float* h2;   hipGetSymbolAddress((void**)&h2, HIP_SYMBOL(g_h2));
  float* h3;   hipGetSymbolAddress((void**)&h3, HIP_SYMBOL(g_h3));
  float* fabp; hipGetSymbolAddress((void**)&fabp, HIP_SYMBOL(g_fab));
  float* gbap; hipGetSymbolAddress((void**)&gbap, HIP_SYMBOL(g_gba));
  float* faap; hipGetSymbolAddress((void**)&faap, HIP_SYMBOL(g_faa));
  float* gbbp; hipGetSymbolAddress((void**)&gbbp, HIP_SYMBOL(g_gbb));
  float* blogp; hipGetSymbolAddress((void**)&blogp, HIP_SYMBOL(g_blog));

  auto fab = [&](int s) { return fabp + (size_t)s * NB * NN; };
  auto gba = [&](int s) { return gbap + (size_t)s * NB * NN; };
  auto faa = [&](int s) { return faap + (size_t)s * NB * NN; };
  auto gbb = [&](int s) { return gbbp + (size_t)s * NB * NN; };

  // eps schedule (matches the Python double loop, then cast to fp32)
  float eps_list[32];
  int ne = 0;
  {
    double v = 64.0 * 64.0;
    double tgt = 0.05 * 0.05;
    while (v > tgt) { eps_list[ne++] = (float)v; v *= 0.25; }
    eps_list[ne++] = (float)tgt;   // ne == 12
  }

  prep_kernel<<<4096, 256, 0, stream>>>(x, y, w1, w2);

  dim3 gg(MM / 128, NN / 128, NB);
  cost_kernel<<<gg, 256, 0, stream>>>(x, y, xn, yn, Cxy);
  cost_kernel<<<gg, 256, 0, stream>>>(y, x, yn, xn, Cyx);   // exact transpose of Cxy
  cost_kernel<<<gg, 256, 0, stream>>>(x, x, xn, xn, Cxx);
  cost_kernel<<<gg, 256, 0, stream>>>(y, y, yn, yn, Cyy);

  dim3 sg(NN, NB);

  auto launch_iter = [&](float eps, float alpha, float beta, float gscale,
                         int in, int outsel) {
    float inv = 1.0f / eps;
    hprep_kernel<<<64, 256, 0, stream>>>(fab(in), gba(in), faa(in), gbb(in),
                                         gscale * inv);
    softmin_row<<<sg, 256, 0, stream>>>(Cxy, h0, fab(in), fab(outsel), eps, inv, alpha, beta);
    softmin_row<<<sg, 256, 0, stream>>>(Cyx, h1, gba(in), gba(outsel), eps, inv, alpha, beta);
    softmin_row<<<sg, 256, 0, stream>>>(Cxx, h2, faa(in), faa(outsel), eps, inv, alpha, beta);
    softmin_row<<<sg, 256, 0, stream>>>(Cyy, h3, gbb(in), gbb(outsel), eps, inv, alpha, beta);
  };

  // init at eps0: f = softmin(eps0, C, base); gscale=0 -> h = base; alpha=0.
  // 'in' buffers are read by hprep with gs=0 and by alpha=0*fold — any
  // initialized buffer works; bank 0 is written by this call, so use blog-
  // filled safety: pass bank 0 (zero-initialized .bss on first call, and
  // fully overwritten before any later read; values never affect output).
  launch_iter(eps_list[0], 0.f, 1.f, 0.f, 0, 0);

  // scan over the full eps list with 0.5-averaging (Jacobi, carry in banks 0/1)
  int cur = 0;
  for (int k = 0; k < ne; ++k) {
    int nxt = 1 - cur;
    launch_iter(eps_list[k], 0.5f, 0.5f, 1.f, cur, nxt);
    cur = nxt;
  }

  // final extrapolation at eps = blur^p (no averaging) -> bank 2
  launch_iter(eps_list[ne - 1], 0.f, 1.f, 1.f, cur, 2);

  loss_kernel<<<1, 256, 0, stream>>>(w1, w2, out);
}

// Round 5
// 1347.080 us; speedup vs baseline: 1.4624x; 1.4624x over previous
//
#include <hip/hip_runtime.h>

#define NB 8
#define NN 2048
#define MM 2048
#define DD 64
#define NMAT ((size_t)NN * (size_t)MM)

// uint16 fixed-point encoding of C: C_true ~ chi^2_64, max over 3.4e7 draws
// ~165; cap 65535/320 = 204.8. Clamp high is harmless for softmin (largest
// costs are the most-negative exponents). Quantum 1/640 after rounding.
#define CSCALE 320.0f
#define CDEC   (1.0f / CSCALE)

// ---------------------------------------------------------------------------
// Static device scratch. Four uint16 cost slabs (Cyx materialized via a
// cost_kernel call with arguments swapped — bit-exact transpose of Cxy).
// ---------------------------------------------------------------------------
__device__ unsigned short g_C[4 * NB * NMAT];   // Cxy|Cyx|Cxx|Cyy, 268 MB
// potential banks: [0]/[1] = carry double-buffer, [2] = final
__device__ float g_fab[3][NB * NN], g_gba[3][NB * NN];
__device__ float g_faa[3][NB * NN], g_gbb[3][NB * NN];
__device__ float g_alog[NB * NN], g_blog[NB * NN];
__device__ float g_xn[NB * NN], g_yn[NB * NN];
__device__ float g_h0[NB * MM], g_h1[NB * NN], g_h2[NB * NN], g_h3[NB * MM];

// ---------------------------------------------------------------------------
// prep: a_log/b_log = log(w), xn/yn = 0.5*||row||^2 (one row per wave)
// ---------------------------------------------------------------------------
__global__ __launch_bounds__(256) void prep_kernel(
    const float* __restrict__ x, const float* __restrict__ y,
    const float* __restrict__ w1, const float* __restrict__ w2)
{
  int gid = blockIdx.x * 256 + threadIdx.x;
  if (gid < NB * NN) {
    g_alog[gid] = logf(w1[gid]);
    g_blog[gid] = logf(w2[gid]);
  }
  int lane = threadIdx.x & 63;
  int row = blockIdx.x * 4 + (threadIdx.x >> 6);   // grid 4096 -> rows 0..16383
  float xv = x[(size_t)row * DD + lane];
  float yv = y[(size_t)row * DD + lane];
  float sx = xv * xv;
  float sy = yv * yv;
#pragma unroll
  for (int off = 32; off > 0; off >>= 1) {
    sx += __shfl_down(sx, off);
    sy += __shfl_down(sy, off);
  }
  if (lane == 0) {
    g_xn[row] = 0.5f * sx;
    g_yn[row] = 0.5f * sy;
  }
}

// ---------------------------------------------------------------------------
// cost GEMM: C[b][i][j] = max(xn_i + yn_j - x_i . y_j, 0), uint16 out.
// 128x128 tile, 256 threads (8x8/thread). BK=32 two-phase staging (32 KB LDS
// -> 4-5 blocks/CU vs 2). LDS row index XOR-swizzled by (k & 28): staging
// stores go 16-way -> ~2-way conflict; A-fragment reads become broadcasts.
// ---------------------------------------------------------------------------
__global__ __launch_bounds__(256) void cost_kernel(
    const float* __restrict__ X, const float* __restrict__ Y,
    const float* __restrict__ xn, const float* __restrict__ yn,
    unsigned short* __restrict__ C)
{
  __shared__ float Xs[32 * 128];
  __shared__ float Ys[32 * 128];
  const int b = blockIdx.z;
  const int i0 = blockIdx.y * 128;
  const int j0 = blockIdx.x * 128;
  const int t = threadIdx.x;
  const float* xb = X + (size_t)b * NN * DD;
  const float* yb = Y + (size_t)b * MM * DD;
  const int tx = t & 15, ty = t >> 4;

  float acc[8][8];
#pragma unroll
  for (int r = 0; r < 8; ++r)
#pragma unroll
    for (int c = 0; c < 8; ++c) acc[r][c] = 0.f;

  for (int kk = 0; kk < 64; kk += 32) {
    if (kk) __syncthreads();   // protect previous phase's reads
#pragma unroll
    for (int p = 0; p < 4; ++p) {
      int f = p * 256 + t;        // float4 slot in 128x32 tile
      int r = f >> 3;             // 0..127
      int k4 = (f & 7) << 2;      // 0,4,...,28 ; swizzle s == k4 here
      float4 vx = ((const float4*)(xb + (size_t)(i0 + r) * DD))[(kk >> 2) + (f & 7)];
      int rs = r ^ k4;            // swizzled row
      Xs[(k4 + 0) * 128 + rs] = vx.x;
      Xs[(k4 + 1) * 128 + rs] = vx.y;
      Xs[(k4 + 2) * 128 + rs] = vx.z;
      Xs[(k4 + 3) * 128 + rs] = vx.w;
      float4 vy = ((const float4*)(yb + (size_t)(j0 + r) * DD))[(kk >> 2) + (f & 7)];
      Ys[(k4 + 0) * 128 + rs] = vy.x;
      Ys[(k4 + 1) * 128 + rs] = vy.y;
      Ys[(k4 + 2) * 128 + rs] = vy.z;
      Ys[(k4 + 3) * 128 + rs] = vy.w;
    }
    __syncthreads();

#pragma unroll 4
    for (int k = 0; k < 32; ++k) {
      int s = k & 28;             // = 4*(k>>2)
      float a[8], bb[8];
      *(float4*)&a[0]  = *(const float4*)&Xs[k * 128 + ((ty * 8) ^ s)];
      *(float4*)&a[4]  = *(const float4*)&Xs[k * 128 + ((ty * 8 + 4) ^ s)];
      *(float4*)&bb[0] = *(const float4*)&Ys[k * 128 + ((tx * 8) ^ s)];
      *(float4*)&bb[4] = *(const float4*)&Ys[k * 128 + ((tx * 8 + 4) ^ s)];
#pragma unroll
      for (int r = 0; r < 8; ++r)
#pragma unroll
        for (int c = 0; c < 8; ++c)
          acc[r][c] = fmaf(a[r], bb[c], acc[r][c]);
    }
  }

  float xr[8], yc[8];
#pragma unroll
  for (int r = 0; r < 8; ++r) xr[r] = xn[b * NN + i0 + ty * 8 + r];
#pragma unroll
  for (int c = 0; c < 8; ++c) yc[c] = yn[b * MM + j0 + tx * 8 + c];

#pragma unroll
  for (int r = 0; r < 8; ++r) {
    unsigned short* crow = C + (size_t)b * NMAT
                         + (size_t)(i0 + ty * 8 + r) * MM + j0 + tx * 8;
    unsigned int u[8];
#pragma unroll
    for (int c = 0; c < 8; ++c) {
      float cv = fmaxf(xr[r] + yc[c] - acc[r][c], 0.f);
      u[c] = __float2uint_rn(fminf(cv * CSCALE, 65535.f));
    }
    uint4 ow;
    ow.x = u[0] | (u[1] << 16);
    ow.y = u[2] | (u[3] << 16);
    ow.z = u[4] | (u[5] << 16);
    ow.w = u[6] | (u[7] << 16);
    *(uint4*)crow = ow;          // 16B aligned: col index % 8 == 0
  }
}

// ---------------------------------------------------------------------------
// h-vector prep for one iteration (all four problems):
//   h0 = blog + gs*gba_in ; h1 = alog + gs*fab_in
//   h2 = alog + gs*faa_in ; h3 = blog + gs*gbb_in
// ---------------------------------------------------------------------------
__global__ __launch_bounds__(256) void hprep_kernel(
    const float* __restrict__ fab_in, const float* __restrict__ gba_in,
    const float* __restrict__ faa_in, const float* __restrict__ gbb_in,
    float gs)
{
  int i = blockIdx.x * 256 + threadIdx.x;   // grid 64 -> 16384
  g_h0[i] = fmaf(gs, gba_in[i], g_blog[i]);
  g_h1[i] = fmaf(gs, fab_in[i], g_alog[i]);
  g_h2[i] = fmaf(gs, faa_in[i], g_alog[i]);
  g_h3[i] = fmaf(gs, gbb_in[i], g_blog[i]);
}

// ---------------------------------------------------------------------------
// row softmin, 4 problems fused on blockIdx.z (body identical to the verified
// round-4 kernel; only the C load is uint16-decoded and per-thread columns
// are contiguous 8-element groups). One block per row, two-phase max/sum.
//   ft = -eps * log sum_j exp(h_j - C[row,j]*inv_eps)
//   fout = alpha*fold + beta*ft
// ---------------------------------------------------------------------------
struct SmArgs {
  const unsigned short* C;
  const float* h;
  const float* fold;
  float* fout;
};

__global__ __launch_bounds__(256) void softmin_row4(
    SmArgs A0, SmArgs A1, SmArgs A2, SmArgs A3,
    float eps, float inv_eps, float alpha, float beta)
{
  SmArgs A = (blockIdx.z == 0) ? A0 : (blockIdx.z == 1) ? A1
           : (blockIdx.z == 2) ? A2 : A3;
  const int b = blockIdx.y;
  const int row = blockIdx.x;
  const int t = threadIdx.x;
  const unsigned short* Crow = A.C + (size_t)b * NMAT + (size_t)row * MM;
  const float* hb = A.h + (size_t)b * MM;
  const float csneg = -inv_eps * CDEC;
  __shared__ float red[256];

  // thread t owns columns 8t..8t+7: one uint4 (8 x u16) + two float4 h loads
  uint4 cr = ((const uint4*)Crow)[t];
  float4 h01 = ((const float4*)hb)[2 * t];
  float4 h23 = ((const float4*)hb)[2 * t + 1];

  float v[8];
  v[0] = fmaf((float)(cr.x & 0xffff), csneg, h01.x);
  v[1] = fmaf((float)(cr.x >> 16),    csneg, h01.y);
  v[2] = fmaf((float)(cr.y & 0xffff), csneg, h01.z);
  v[3] = fmaf((float)(cr.y >> 16),    csneg, h01.w);
  v[4] = fmaf((float)(cr.z & 0xffff), csneg, h23.x);
  v[5] = fmaf((float)(cr.z >> 16),    csneg, h23.y);
  v[6] = fmaf((float)(cr.w & 0xffff), csneg, h23.z);
  v[7] = fmaf((float)(cr.w >> 16),    csneg, h23.w);

  float m = v[0];
#pragma unroll
  for (int q = 1; q < 8; ++q) m = fmaxf(m, v[q]);
  red[t] = m;
  __syncthreads();
  for (int s = 128; s > 0; s >>= 1) {
    if (t < s) red[t] = fmaxf(red[t], red[t + s]);
    __syncthreads();
  }
  float M = red[0];
  __syncthreads();

  float sum = 0.f;
#pragma unroll
  for (int q = 0; q < 8; ++q) sum += __expf(v[q] - M);
  red[t] = sum;
  __syncthreads();
  for (int s = 128; s > 0; s >>= 1) {
    if (t < s) red[t] += red[t + s];
    __syncthreads();
  }
  if (t == 0) {
    float ft = -eps * (M + __logf(red[0]));
    int idx = b * NN + row;
    A.fout[idx] = alpha * A.fold[idx] + beta * ft;
  }
}

// ---------------------------------------------------------------------------
// loss = mean_b [ sum_i w1*(fabf - faaf) + sum_j w2*(gbaf - gbbf) ]
// ---------------------------------------------------------------------------
__global__ __launch_bounds__(256) void loss_kernel(
    const float* __restrict__ w1, const float* __restrict__ w2,
    float* __restrict__ out)
{
  __shared__ float red[256];
  float acc = 0.f;
  for (int idx = threadIdx.x; idx < NB * NN; idx += 256) {
    acc += w1[idx] * (g_fab[2][idx] - g_faa[2][idx])
         + w2[idx] * (g_gba[2][idx] - g_gbb[2][idx]);
  }
  red[threadIdx.x] = acc;
  __syncthreads();
  for (int s = 128; s > 0; s >>= 1) {
    if (threadIdx.x < s) red[threadIdx.x] += red[threadIdx.x + s];
    __syncthreads();
  }
  if (threadIdx.x == 0) out[0] = red[0] * (1.0f / NB);
}

// ---------------------------------------------------------------------------
extern "C" void kernel_launch(void* const* d_in, const int* in_sizes, int n_in,
                              void* d_out, int out_size, void* d_ws, size_t ws_size,
                              hipStream_t stream)
{
  const float* x = (const float*)d_in[0];
  const float* y = (const float*)d_in[1];
  const float* w1 = (const float*)d_in[2];
  const float* w2 = (const float*)d_in[3];
  float* out = (float*)d_out;

  unsigned short* Cbase;
  hipGetSymbolAddress((void**)&Cbase, HIP_SYMBOL(g_C));
  unsigned short* Cxy = Cbase + 0ull * NB * NMAT;
  unsigned short* Cyx = Cbase + 1ull * NB * NMAT;
  unsigned short* Cxx = Cbase + 2ull * NB * NMAT;
  unsigned short* Cyy = Cbase + 3ull * NB * NMAT;
  float *xn, *yn, *h0, *h1, *h2, *h3, *fabp, *gbap, *faap, *gbbp;
  hipGetSymbolAddress((void**)&xn, HIP_SYMBOL(g_xn));
  hipGetSymbolAddress((void**)&yn, HIP_SYMBOL(g_yn));
  hipGetSymbolAddress((void**)&h0, HIP_SYMBOL(g_h0));
  hipGetSymbolAddress((void**)&h1, HIP_SYMBOL(g_h1));
  hipGetSymbolAddress((void**)&h2, HIP_SYMBOL(g_h2));
  hipGetSymbolAddress((void**)&h3, HIP_SYMBOL(g_h3));
  hipGetSymbolAddress((void**)&fabp, HIP_SYMBOL(g_fab));
  hipGetSymbolAddress((void**)&gbap, HIP_SYMBOL(g_gba));
  hipGetSymbolAddress((void**)&faap, HIP_SYMBOL(g_faa));
  hipGetSymbolAddress((void**)&gbbp, HIP_SYMBOL(g_gbb));

  auto fab = [&](int s) { return fabp + (size_t)s * NB * NN; };
  auto gba = [&](int s) { return gbap + (size_t)s * NB * NN; };
  auto faa = [&](int s) { return faap + (size_t)s * NB * NN; };
  auto gbb = [&](int s) { return gbbp + (size_t)s * NB * NN; };

  // eps schedule (matches the Python double loop, then cast to fp32)
  float eps_list[32];
  int ne = 0;
  {
    double v = 64.0 * 64.0;
    double tgt = 0.05 * 0.05;
    while (v > tgt) { eps_list[ne++] = (float)v; v *= 0.25; }
    eps_list[ne++] = (float)tgt;   // ne == 12
  }

  prep_kernel<<<4096, 256, 0, stream>>>(x, y, w1, w2);

  dim3 gg(MM / 128, NN / 128, NB);
  cost_kernel<<<gg, 256, 0, stream>>>(x, y, xn, yn, Cxy);
  cost_kernel<<<gg, 256, 0, stream>>>(y, x, yn, xn, Cyx);   // exact transpose of Cxy
  cost_kernel<<<gg, 256, 0, stream>>>(x, x, xn, xn, Cxx);
  cost_kernel<<<gg, 256, 0, stream>>>(y, y, yn, yn, Cyy);

  dim3 sg(NN, NB, 4);

  auto launch_iter = [&](float eps, float alpha, float beta, float gscale,
                         int in, int outsel) {
    float inv = 1.0f / eps;
    hprep_kernel<<<64, 256, 0, stream>>>(fab(in), gba(in), faa(in), gbb(in),
                                         gscale * inv);
    SmArgs A0 = {Cxy, h0, fab(in), fab(outsel)};
    SmArgs A1 = {Cyx, h1, gba(in), gba(outsel)};
    SmArgs A2 = {Cxx, h2, faa(in), faa(outsel)};
    SmArgs A3 = {Cyy, h3, gbb(in), gbb(outsel)};
    softmin_row4<<<sg, 256, 0, stream>>>(A0, A1, A2, A3, eps, inv, alpha, beta);
  };

  // init at eps0: gscale=0 -> h = base log-weights; alpha=0 -> no carry read.
  // Bank 0 contents (stale or zero) are multiplied by 0 in both paths.
  launch_iter(eps_list[0], 0.f, 1.f, 0.f, 0, 0);

  // scan over the full eps list with 0.5-averaging (Jacobi, banks 0/1)
  int cur = 0;
  for (int k = 0; k < ne; ++k) {
    int nxt = 1 - cur;
    launch_iter(eps_list[k], 0.5f, 0.5f, 1.f, cur, nxt);
    cur = nxt;
  }

  // final extrapolation at eps = blur^p (no averaging) -> bank 2
  launch_iter(eps_list[ne - 1], 0.f, 1.f, 1.f, cur, 2);

  loss_kernel<<<1, 256, 0, stream>>>(w1, w2, out);
}

// Round 6
// 1014.424 us; speedup vs baseline: 1.9420x; 1.3279x over previous
//
#include <hip/hip_runtime.h>

#define NB 8
#define NN 2048
#define MM 2048
#define DD 64
#define NMAT ((size_t)NN * (size_t)MM)
#define NCH 32
#define CHROWS (NN / NCH)   // 64

// uint16 fixed-point encoding of C (exact enough: round-5 absmax was 0.0)
#define CSCALE 320.0f
#define CDEC   (1.0f / CSCALE)

// ---------------------------------------------------------------------------
// Static device scratch. THREE u16 cost slabs (201 MB -> fits 256 MB L3).
// g_ba's softmin over C_yx is done as a column pass over C_xy.
// ---------------------------------------------------------------------------
__device__ unsigned short g_C[3 * NB * NMAT];   // Cxy|Cxx|Cyy
// potential banks: [0]/[1] = carry double-buffer, [2] = final
__device__ float g_fab[3][NB * NN], g_gba[3][NB * NN];
__device__ float g_faa[3][NB * NN], g_gbb[3][NB * NN];
__device__ float g_alog[NB * NN], g_blog[NB * NN];
__device__ float g_xn[NB * NN], g_yn[NB * NN];
__device__ float g_h0[NB * MM], g_h1[NB * NN], g_h2[NB * NN], g_h3[NB * MM];
__device__ float g_pm[NB * NCH * MM], g_ps[NB * NCH * MM];

// ---------------------------------------------------------------------------
// prep: a_log/b_log = log(w), xn/yn = 0.5*||row||^2 (one row per wave)
// ---------------------------------------------------------------------------
__global__ __launch_bounds__(256) void prep_kernel(
    const float* __restrict__ x, const float* __restrict__ y,
    const float* __restrict__ w1, const float* __restrict__ w2)
{
  int gid = blockIdx.x * 256 + threadIdx.x;
  if (gid < NB * NN) {
    g_alog[gid] = logf(w1[gid]);
    g_blog[gid] = logf(w2[gid]);
  }
  int lane = threadIdx.x & 63;
  int row = blockIdx.x * 4 + (threadIdx.x >> 6);   // grid 4096 -> rows 0..16383
  float xv = x[(size_t)row * DD + lane];
  float yv = y[(size_t)row * DD + lane];
  float sx = xv * xv;
  float sy = yv * yv;
#pragma unroll
  for (int off = 32; off > 0; off >>= 1) {
    sx += __shfl_down(sx, off);
    sy += __shfl_down(sy, off);
  }
  if (lane == 0) {
    g_xn[row] = 0.5f * sx;
    g_yn[row] = 0.5f * sy;
  }
}

// ---------------------------------------------------------------------------
// cost GEMM: C[b][i][j] = max(xn_i + yn_j - x_i . y_j, 0), uint16 out.
// 128x128 tile, 256 threads (8x8/thread). BK=32, XOR-swizzled LDS (round 5).
// ---------------------------------------------------------------------------
__global__ __launch_bounds__(256) void cost_kernel(
    const float* __restrict__ X, const float* __restrict__ Y,
    const float* __restrict__ xn, const float* __restrict__ yn,
    unsigned short* __restrict__ C)
{
  __shared__ float Xs[32 * 128];
  __shared__ float Ys[32 * 128];
  const int b = blockIdx.z;
  const int i0 = blockIdx.y * 128;
  const int j0 = blockIdx.x * 128;
  const int t = threadIdx.x;
  const float* xb = X + (size_t)b * NN * DD;
  const float* yb = Y + (size_t)b * MM * DD;
  const int tx = t & 15, ty = t >> 4;

  float acc[8][8];
#pragma unroll
  for (int r = 0; r < 8; ++r)
#pragma unroll
    for (int c = 0; c < 8; ++c) acc[r][c] = 0.f;

  for (int kk = 0; kk < 64; kk += 32) {
    if (kk) __syncthreads();
#pragma unroll
    for (int p = 0; p < 4; ++p) {
      int f = p * 256 + t;
      int r = f >> 3;
      int k4 = (f & 7) << 2;
      float4 vx = ((const float4*)(xb + (size_t)(i0 + r) * DD))[(kk >> 2) + (f & 7)];
      int rs = r ^ k4;
      Xs[(k4 + 0) * 128 + rs] = vx.x;
      Xs[(k4 + 1) * 128 + rs] = vx.y;
      Xs[(k4 + 2) * 128 + rs] = vx.z;
      Xs[(k4 + 3) * 128 + rs] = vx.w;
      float4 vy = ((const float4*)(yb + (size_t)(j0 + r) * DD))[(kk >> 2) + (f & 7)];
      Ys[(k4 + 0) * 128 + rs] = vy.x;
      Ys[(k4 + 1) * 128 + rs] = vy.y;
      Ys[(k4 + 2) * 128 + rs] = vy.z;
      Ys[(k4 + 3) * 128 + rs] = vy.w;
    }
    __syncthreads();

#pragma unroll 4
    for (int k = 0; k < 32; ++k) {
      int s = k & 28;
      float a[8], bb[8];
      *(float4*)&a[0]  = *(const float4*)&Xs[k * 128 + ((ty * 8) ^ s)];
      *(float4*)&a[4]  = *(const float4*)&Xs[k * 128 + ((ty * 8 + 4) ^ s)];
      *(float4*)&bb[0] = *(const float4*)&Ys[k * 128 + ((tx * 8) ^ s)];
      *(float4*)&bb[4] = *(const float4*)&Ys[k * 128 + ((tx * 8 + 4) ^ s)];
#pragma unroll
      for (int r = 0; r < 8; ++r)
#pragma unroll
        for (int c = 0; c < 8; ++c)
          acc[r][c] = fmaf(a[r], bb[c], acc[r][c]);
    }
  }

  float xr[8], yc[8];
#pragma unroll
  for (int r = 0; r < 8; ++r) xr[r] = xn[b * NN + i0 + ty * 8 + r];
#pragma unroll
  for (int c = 0; c < 8; ++c) yc[c] = yn[b * MM + j0 + tx * 8 + c];

#pragma unroll
  for (int r = 0; r < 8; ++r) {
    unsigned short* crow = C + (size_t)b * NMAT
                         + (size_t)(i0 + ty * 8 + r) * MM + j0 + tx * 8;
    unsigned int u[8];
#pragma unroll
    for (int c = 0; c < 8; ++c) {
      float cv = fmaxf(xr[r] + yc[c] - acc[r][c], 0.f);
      u[c] = __float2uint_rn(fminf(cv * CSCALE, 65535.f));
    }
    uint4 ow;
    ow.x = u[0] | (u[1] << 16);
    ow.y = u[2] | (u[3] << 16);
    ow.z = u[4] | (u[5] << 16);
    ow.w = u[6] | (u[7] << 16);
    *(uint4*)crow = ow;
  }
}

// ---------------------------------------------------------------------------
// h-vector prep (unchanged, verified):
//   h0 = blog + gs*gba_in ; h1 = alog + gs*fab_in
//   h2 = alog + gs*faa_in ; h3 = blog + gs*gbb_in
// ---------------------------------------------------------------------------
__global__ __launch_bounds__(256) void hprep_kernel(
    const float* __restrict__ fab_in, const float* __restrict__ gba_in,
    const float* __restrict__ faa_in, const float* __restrict__ gbb_in,
    float gs)
{
  int i = blockIdx.x * 256 + threadIdx.x;   // grid 64 -> 16384
  g_h0[i] = fmaf(gs, gba_in[i], g_blog[i]);
  g_h1[i] = fmaf(gs, fab_in[i], g_alog[i]);
  g_h2[i] = fmaf(gs, faa_in[i], g_alog[i]);
  g_h3[i] = fmaf(gs, gbb_in[i], g_blog[i]);
}

// ---------------------------------------------------------------------------
// row softmin, wave-per-row, no barriers. 3 problems on blockIdx.z
// (Cxy->fab, Cxx->faa, Cyy->gbb). 4 waves/block, 4 rows/wave; h (2048 f32)
// loaded once per wave into registers, amortized over the 4 rows.
//   ft = -eps * log sum_j exp(h_j - C[row,j]*CDEC*inv_eps)
//   fout = alpha*fold + beta*ft
// ---------------------------------------------------------------------------
struct SmArgs {
  const unsigned short* C;
  const float* h;
  const float* fold;
  float* fout;
};

__global__ __launch_bounds__(256) void row_softmin(
    SmArgs A0, SmArgs A1, SmArgs A2,
    float eps, float inv_eps, float alpha, float beta)
{
  SmArgs A = (blockIdx.z == 0) ? A0 : (blockIdx.z == 1) ? A1 : A2;
  const int b = blockIdx.y;
  const int lane = threadIdx.x & 63;
  const int wv = threadIdx.x >> 6;
  const float csneg = -inv_eps * CDEC;
  const unsigned short* Cb = A.C + (size_t)b * NMAT;
  const float4* hb4 = (const float4*)(A.h + (size_t)b * MM);

  // lane owns cols 8*(tq*64+lane)..+7 for tq<4  (matches uint4 C loads)
  float h[4][8];
#pragma unroll
  for (int tq = 0; tq < 4; ++tq) {
    int f = tq * 64 + lane;
    float4 ha = hb4[2 * f];
    float4 hbv = hb4[2 * f + 1];
    h[tq][0] = ha.x;  h[tq][1] = ha.y;  h[tq][2] = ha.z;  h[tq][3] = ha.w;
    h[tq][4] = hbv.x; h[tq][5] = hbv.y; h[tq][6] = hbv.z; h[tq][7] = hbv.w;
  }

#pragma unroll 1
  for (int r = 0; r < 4; ++r) {
    int row = blockIdx.x * 16 + wv * 4 + r;
    const uint4* c4 = (const uint4*)(Cb + (size_t)row * MM);
    float v[4][8];
    float m = -3.0e38f;
#pragma unroll
    for (int tq = 0; tq < 4; ++tq) {
      uint4 cu = c4[tq * 64 + lane];
      v[tq][0] = fmaf((float)(cu.x & 0xffff), csneg, h[tq][0]);
      v[tq][1] = fmaf((float)(cu.x >> 16),    csneg, h[tq][1]);
      v[tq][2] = fmaf((float)(cu.y & 0xffff), csneg, h[tq][2]);
      v[tq][3] = fmaf((float)(cu.y >> 16),    csneg, h[tq][3]);
      v[tq][4] = fmaf((float)(cu.z & 0xffff), csneg, h[tq][4]);
      v[tq][5] = fmaf((float)(cu.z >> 16),    csneg, h[tq][5]);
      v[tq][6] = fmaf((float)(cu.w & 0xffff), csneg, h[tq][6]);
      v[tq][7] = fmaf((float)(cu.w >> 16),    csneg, h[tq][7]);
#pragma unroll
      for (int k = 0; k < 8; ++k) m = fmaxf(m, v[tq][k]);
    }
    // wave max
#pragma unroll
    for (int off = 32; off > 0; off >>= 1)
      m = fmaxf(m, __shfl_down(m, off));
    float M = __shfl(m, 0);

    float s = 0.f;
#pragma unroll
    for (int tq = 0; tq < 4; ++tq)
#pragma unroll
      for (int k = 0; k < 8; ++k)
        s += __expf(v[tq][k] - M);
    // wave sum
#pragma unroll
    for (int off = 32; off > 0; off >>= 1)
      s += __shfl_down(s, off);

    if (lane == 0) {
      float ft = -eps * (M + __logf(s));
      int idx = b * NN + row;
      A.fout[idx] = alpha * A.fold[idx] + beta * ft;
    }
  }
}

// ---------------------------------------------------------------------------
// column softmin over C_xy (== softmin over C_yx rows), chunked partials.
//   gt_j = -eps log sum_i exp(h1_i - Cxy[i,j]/eps)
// Thread owns 2 adjacent cols (one uint load/row, coalesced). h1[i] is
// block-uniform -> scalar loads. NCH=32 chunks of 64 rows -> 1024 blocks.
// ---------------------------------------------------------------------------
__global__ __launch_bounds__(256) void col_partial(
    const unsigned short* __restrict__ C, const float* __restrict__ h,
    float inv_eps)
{
  const int b = blockIdx.z;
  const int chunk = blockIdx.y;
  const int j2 = blockIdx.x * 256 + threadIdx.x;   // uint index; grid.x = MM/512
  const float csneg = -inv_eps * CDEC;
  const float* hb = h + (size_t)b * NN;
  const unsigned int* Cu = (const unsigned int*)(C + (size_t)b * NMAT
                           + (size_t)chunk * CHROWS * MM) + j2;

  float m0 = -3.0e38f, m1 = -3.0e38f, s0 = 0.f, s1 = 0.f;
#pragma unroll 4
  for (int i = 0; i < CHROWS; ++i) {
    float hv = hb[chunk * CHROWS + i];         // block-uniform -> s_load
    unsigned int cu = Cu[(size_t)i * (MM / 2)];
    float v0 = fmaf((float)(cu & 0xffff), csneg, hv);
    float v1 = fmaf((float)(cu >> 16),    csneg, hv);
    float n0 = fmaxf(m0, v0);
    float n1 = fmaxf(m1, v1);
    s0 = s0 * __expf(m0 - n0) + __expf(v0 - n0);
    s1 = s1 * __expf(m1 - n1) + __expf(v1 - n1);
    m0 = n0; m1 = n1;
  }
  int idx = (b * NCH + chunk) * MM + 2 * j2;
  *(float2*)&g_pm[idx] = make_float2(m0, m1);
  *(float2*)&g_ps[idx] = make_float2(s0, s1);
}

__global__ __launch_bounds__(256) void col_merge(
    const float* __restrict__ gold, float* __restrict__ gout,
    float eps, float alpha, float beta)
{
  const int b = blockIdx.y;
  const int j = blockIdx.x * 256 + threadIdx.x;   // grid.x = MM/256
  float pm[NCH], ps[NCH];
#pragma unroll
  for (int c = 0; c < NCH; ++c) {
    pm[c] = g_pm[(b * NCH + c) * MM + j];
    ps[c] = g_ps[(b * NCH + c) * MM + j];
  }
  float M = pm[0];
#pragma unroll
  for (int c = 1; c < NCH; ++c) M = fmaxf(M, pm[c]);
  float S = 0.f;
#pragma unroll
  for (int c = 0; c < NCH; ++c) S += ps[c] * __expf(pm[c] - M);
  float gt = -eps * (M + __logf(S));
  int idx = b * MM + j;
  gout[idx] = alpha * gold[idx] + beta * gt;
}

// ---------------------------------------------------------------------------
// loss = mean_b [ sum_i w1*(fabf - faaf) + sum_j w2*(gbaf - gbbf) ]
// ---------------------------------------------------------------------------
__global__ __launch_bounds__(256) void loss_kernel(
    const float* __restrict__ w1, const float* __restrict__ w2,
    float* __restrict__ out)
{
  __shared__ float red[256];
  float acc = 0.f;
  for (int idx = threadIdx.x; idx < NB * NN; idx += 256) {
    acc += w1[idx] * (g_fab[2][idx] - g_faa[2][idx])
         + w2[idx] * (g_gba[2][idx] - g_gbb[2][idx]);
  }
  red[threadIdx.x] = acc;
  __syncthreads();
  for (int s = 128; s > 0; s >>= 1) {
    if (threadIdx.x < s) red[threadIdx.x] += red[threadIdx.x + s];
    __syncthreads();
  }
  if (threadIdx.x == 0) out[0] = red[0] * (1.0f / NB);
}

// ---------------------------------------------------------------------------
extern "C" void kernel_launch(void* const* d_in, const int* in_sizes, int n_in,
                              void* d_out, int out_size, void* d_ws, size_t ws_size,
                              hipStream_t stream)
{
  const float* x = (const float*)d_in[0];
  const float* y = (const float*)d_in[1];
  const float* w1 = (const float*)d_in[2];
  const float* w2 = (const float*)d_in[3];
  float* out = (float*)d_out;

  unsigned short* Cbase;
  hipGetSymbolAddress((void**)&Cbase, HIP_SYMBOL(g_C));
  unsigned short* Cxy = Cbase + 0ull * NB * NMAT;
  unsigned short* Cxx = Cbase + 1ull * NB * NMAT;
  unsigned short* Cyy = Cbase + 2ull * NB * NMAT;
  float *xn, *yn, *h0, *h1, *h2, *h3, *fabp, *gbap, *faap, *gbbp;
  hipGetSymbolAddress((void**)&xn, HIP_SYMBOL(g_xn));
  hipGetSymbolAddress((void**)&yn, HIP_SYMBOL(g_yn));
  hipGetSymbolAddress((void**)&h0, HIP_SYMBOL(g_h0));
  hipGetSymbolAddress((void**)&h1, HIP_SYMBOL(g_h1));
  hipGetSymbolAddress((void**)&h2, HIP_SYMBOL(g_h2));
  hipGetSymbolAddress((void**)&h3, HIP_SYMBOL(g_h3));
  hipGetSymbolAddress((void**)&fabp, HIP_SYMBOL(g_fab));
  hipGetSymbolAddress((void**)&gbap, HIP_SYMBOL(g_gba));
  hipGetSymbolAddress((void**)&faap, HIP_SYMBOL(g_faa));
  hipGetSymbolAddress((void**)&gbbp, HIP_SYMBOL(g_gbb));

  auto fab = [&](int s) { return fabp + (size_t)s * NB * NN; };
  auto gba = [&](int s) { return gbap + (size_t)s * NB * NN; };
  auto faa = [&](int s) { return faap + (size_t)s * NB * NN; };
  auto gbb = [&](int s) { return gbbp + (size_t)s * NB * NN; };

  // eps schedule (matches the Python double loop, then cast to fp32)
  float eps_list[32];
  int ne = 0;
  {
    double v = 64.0 * 64.0;
    double tgt = 0.05 * 0.05;
    while (v > tgt) { eps_list[ne++] = (float)v; v *= 0.25; }
    eps_list[ne++] = (float)tgt;   // ne == 12
  }

  prep_kernel<<<4096, 256, 0, stream>>>(x, y, w1, w2);

  dim3 gg(MM / 128, NN / 128, NB);
  cost_kernel<<<gg, 256, 0, stream>>>(x, y, xn, yn, Cxy);
  cost_kernel<<<gg, 256, 0, stream>>>(x, x, xn, xn, Cxx);
  cost_kernel<<<gg, 256, 0, stream>>>(y, y, yn, yn, Cyy);

  dim3 rg(NN / 16, NB, 3);
  dim3 cg(MM / 512, NCH, NB);
  dim3 mg(MM / 256, NB);

  auto launch_iter = [&](float eps, float alpha, float beta, float gscale,
                         int in, int outsel) {
    float inv = 1.0f / eps;
    hprep_kernel<<<64, 256, 0, stream>>>(fab(in), gba(in), faa(in), gbb(in),
                                         gscale * inv);
    SmArgs A0 = {Cxy, h0, fab(in), fab(outsel)};
    SmArgs A1 = {Cxx, h2, faa(in), faa(outsel)};
    SmArgs A2 = {Cyy, h3, gbb(in), gbb(outsel)};
    row_softmin<<<rg, 256, 0, stream>>>(A0, A1, A2, eps, inv, alpha, beta);
    col_partial<<<cg, 256, 0, stream>>>(Cxy, h1, inv);
    col_merge<<<mg, 256, 0, stream>>>(gba(in), gba(outsel), eps, alpha, beta);
  };

  // init at eps0: gscale=0 -> h = base log-weights; alpha=0 -> no carry read.
  launch_iter(eps_list[0], 0.f, 1.f, 0.f, 0, 0);

  // scan over the full eps list with 0.5-averaging (Jacobi, banks 0/1)
  int cur = 0;
  for (int k = 0; k < ne; ++k) {
    int nxt = 1 - cur;
    launch_iter(eps_list[k], 0.5f, 0.5f, 1.f, cur, nxt);
    cur = nxt;
  }

  // final extrapolation at eps = blur^p (no averaging) -> bank 2
  launch_iter(eps_list[ne - 1], 0.f, 1.f, 1.f, cur, 2);

  loss_kernel<<<1, 256, 0, stream>>>(w1, w2, out);
}